// Round 14
// baseline (1205.207 us; speedup 1.0000x reference)
//
#include <hip/hip_runtime.h>
#include <float.h>
#include <math.h>

// ======================= DIAGNOSTIC ROUND 2 =======================
// R13 kernels bit-identical; k1/k3/k6 repeated (idempotent) to lift them
// above the ~155us fill rows in rocprof top-5. True time = shown / REP.
#define REP1_ 8
#define REP3_ 8
#define REP6_ 4

#define B_ 32
#define S_ 2048
#define H_ 1024
#define M_ 128
#define N_ 500000
#define KK 16
#define KK2 32
#define ALPHA_ 0.1f
#define TAU_ 0.1f
#define EPS_ 1e-5f
#define MAX_NORM_ 0.99999f
#define MAXN2_ (MAX_NORM_ * MAX_NORM_)
#define SC_ 64
#define RPB_ 256
#define NBLK_ ((N_ + RPB_ - 1) / RPB_)   // 1954
#define WIN_ 2048
#define NWIN_ ((N_ + WIN_ - 1) / WIN_)   // 245
#define NPAD_ (NWIN_ * WIN_)             // 501760

typedef __attribute__((ext_vector_type(8))) short short8;
typedef __attribute__((ext_vector_type(4))) float f32x4;

__device__ __forceinline__ unsigned short to_bf16_rz(float x) {
    return (unsigned short)(__float_as_uint(x) >> 16);
}

// ---------------------------------------------------------------- k1: pool partial sums
__global__ __launch_bounds__(256) void k1_pool(const float* __restrict__ hid,
                                               float* __restrict__ pp) {
    int bid = blockIdx.x;
    int b = bid >> 6, sc = bid & 63;
    const float4* h4 = (const float4*)hid + (((size_t)(b * S_ + sc * (S_ / SC_))) << 8) + threadIdx.x;
    #pragma unroll 1
    for (int rep = 0; rep < REP1_; ++rep) {
        asm volatile("" ::: "memory");
        float4 a0 = {0.f, 0.f, 0.f, 0.f}, a1 = a0, a2 = a0, a3 = a0;
        #pragma unroll
        for (int s = 0; s < S_ / SC_; s += 4) {
            float4 v0 = h4[(size_t)(s + 0) << 8];
            float4 v1 = h4[(size_t)(s + 1) << 8];
            float4 v2 = h4[(size_t)(s + 2) << 8];
            float4 v3 = h4[(size_t)(s + 3) << 8];
            a0.x += v0.x; a0.y += v0.y; a0.z += v0.z; a0.w += v0.w;
            a1.x += v1.x; a1.y += v1.y; a1.z += v1.z; a1.w += v1.w;
            a2.x += v2.x; a2.y += v2.y; a2.z += v2.z; a2.w += v2.w;
            a3.x += v3.x; a3.y += v3.y; a3.z += v3.z; a3.w += v3.w;
        }
        float4 acc;
        acc.x = (a0.x + a1.x) + (a2.x + a3.x);
        acc.y = (a0.y + a1.y) + (a2.y + a3.y);
        acc.z = (a0.z + a1.z) + (a2.z + a3.z);
        acc.w = (a0.w + a1.w) + (a2.w + a3.w);
        ((float4*)pp)[(size_t)(b * SC_ + sc) * 256 + threadIdx.x] = acc;
    }
}

// ---------------------------------------------------------------- k2: query network
__device__ __forceinline__ float bred256(float v, volatile float* red, int tid) {
    red[tid] = v;
    __syncthreads();
    if (tid < 64) {
        float x = red[tid] + red[tid + 64] + red[tid + 128] + red[tid + 192];
        #pragma unroll
        for (int off = 32; off >= 1; off >>= 1) x += __shfl_down(x, off);
        if (tid == 0) red[0] = x;
    }
    __syncthreads();
    float r = red[0];
    __syncthreads();
    return r;
}

__global__ __launch_bounds__(256) void k2_query(const float* __restrict__ pp,
                         const float* __restrict__ W1,
                         const float* __restrict__ b1, const float* __restrict__ ln_g,
                         const float* __restrict__ ln_b, const float* __restrict__ W2,
                         const float* __restrict__ b2, const float* __restrict__ qorig,
                         float* __restrict__ query, float* __restrict__ qstats) {
    __shared__ float pooled[H_];
    __shared__ float red[256];
    __shared__ float hv[M_];
    int b = blockIdx.x, tid = threadIdx.x;
    #pragma unroll
    for (int j = 0; j < H_ / 256; ++j) {
        int h = tid + j * 256;
        float s = 0.f;
        for (int sc = 0; sc < SC_; ++sc) s += pp[(size_t)(b * SC_ + sc) * H_ + h];
        pooled[h] = s * (1.0f / (float)S_);
    }
    __syncthreads();
    int m = tid & 127, half = tid >> 7;
    {
        const float* wcol = W1 + m;
        int k0 = half * (H_ / 2);
        float a0 = 0.f, a1 = 0.f, a2 = 0.f, a3 = 0.f;
        #pragma unroll 4
        for (int k = k0; k < k0 + H_ / 2; k += 4) {
            a0 = fmaf(pooled[k + 0], wcol[(k + 0) * M_], a0);
            a1 = fmaf(pooled[k + 1], wcol[(k + 1) * M_], a1);
            a2 = fmaf(pooled[k + 2], wcol[(k + 2) * M_], a2);
            a3 = fmaf(pooled[k + 3], wcol[(k + 3) * M_], a3);
        }
        red[tid] = (a0 + a1) + (a2 + a3);
    }
    __syncthreads();
    float x = (tid < M_) ? (red[m] + red[m + 128] + b1[m]) : 0.f;
    __syncthreads();
    float mu = bred256(x, red, tid) * (1.0f / (float)M_);
    float dmu = (tid < M_) ? (x - mu) : 0.f;
    float var = bred256(dmu * dmu, red, tid) * (1.0f / (float)M_);
    float lg = (tid < M_) ? ln_g[m] : 0.f;
    float lb = (tid < M_) ? ln_b[m] : 0.f;
    float xh = dmu * rsqrtf(var + 1e-5f) * lg + lb;
    float g = 0.5f * xh * (1.0f + erff(xh * 0.70710678f));
    if (tid < M_) hv[m] = g;
    __syncthreads();
    float t = 0.f;
    if (tid < M_) {
        const float* wcol = W2 + m;
        float a0 = b2[m], a1 = 0.f, a2 = 0.f, a3 = 0.f;
        #pragma unroll 4
        for (int k = 0; k < M_; k += 4) {
            a0 = fmaf(hv[k + 0], wcol[(k + 0) * M_], a0);
            a1 = fmaf(hv[k + 1], wcol[(k + 1) * M_], a1);
            a2 = fmaf(hv[k + 2], wcol[(k + 2) * M_], a2);
            a3 = fmaf(hv[k + 3], wcol[(k + 3) * M_], a3);
        }
        t = (a0 + a1) + (a2 + a3);
    }
    float o = (tid < M_) ? qorig[m] : 0.f;
    float on2 = bred256(o * o, red, tid);
    float on = fmaxf(sqrtf(on2), EPS_);
    float osc = 1.0f / fmaxf(on / MAX_NORM_, 1.0f);
    float u = o * osc;
    float vn2 = bred256(t * t, red, tid);
    float vn = fmaxf(sqrtf(vn2), EPS_);
    float sec = tanhf(vn * 0.5f) * t / vn;
    float dot_uv = bred256(u * sec, red, tid);
    float nu = fminf(fmaxf(bred256(u * u, red, tid), 0.f), MAXN2_);
    float nv = fminf(fmaxf(bred256(sec * sec, red, tid), 0.f), MAXN2_);
    float num = (1.0f + 2.0f * dot_uv + nv) * u + (1.0f - nu) * sec;
    float den = 1.0f + 2.0f * dot_uv + nu * nv;
    float r = num / fmaxf(den, EPS_);
    float rn2 = bred256(r * r, red, tid);
    float rn = fmaxf(sqrtf(rn2), EPS_);
    float rsc = 1.0f / fmaxf(rn / MAX_NORM_, 1.0f);
    float q = r * rsc;
    if (tid < M_) query[b * M_ + m] = q;
    float qq = bred256(q * q, red, tid);
    if (tid == 0) {
        qstats[b * 2 + 0] = qq;
        float qn = fminf(fmaxf(qq, 0.f), MAXN2_);
        qstats[b * 2 + 1] = 1.0f - qn;
    }
}

// ---------------------------------------------------------------- k3: MFMA scorer
__global__ __launch_bounds__(256, 3) void k3_scores(const float* __restrict__ mem,
                                                    const float* __restrict__ query,
                                                    const float* __restrict__ qstats,
                                                    unsigned short* __restrict__ keyplane) {
    __shared__ unsigned short key_lds[B_][264];
    __shared__ float mm_lds[256];
    __shared__ float qq_s[B_], omq_s[B_];
    int tid = threadIdx.x, bid = blockIdx.x;
    int wave = tid >> 6, lane = tid & 63;
    int l15 = lane & 15, lk = lane >> 4;

    if (tid < B_) { qq_s[tid] = qstats[tid * 2]; omq_s[tid] = qstats[tid * 2 + 1]; }

    short8 bfrag[2][4];
    #pragma unroll
    for (int bg = 0; bg < 2; ++bg) {
        #pragma unroll
        for (int kt = 0; kt < 4; ++kt) {
            int batch = bg * 16 + l15;
            const float4* qp = (const float4*)(query + batch * M_ + kt * 32 + lk * 8);
            float4 lo = qp[0], hi = qp[1];
            short8 f;
            f[0] = (short)to_bf16_rz(lo.x); f[1] = (short)to_bf16_rz(lo.y);
            f[2] = (short)to_bf16_rz(lo.z); f[3] = (short)to_bf16_rz(lo.w);
            f[4] = (short)to_bf16_rz(hi.x); f[5] = (short)to_bf16_rz(hi.y);
            f[6] = (short)to_bf16_rz(hi.z); f[7] = (short)to_bf16_rz(hi.w);
            bfrag[bg][kt] = f;
        }
    }

    int passbase = bid * RPB_;
    #pragma unroll 1
    for (int rep = 0; rep < REP3_; ++rep) {
        asm volatile("" ::: "memory");
        f32x4 acc[4][2];
        #pragma unroll
        for (int rg = 0; rg < 4; ++rg)
            #pragma unroll
            for (int bg = 0; bg < 2; ++bg)
                acc[rg][bg] = (f32x4){0.f, 0.f, 0.f, 0.f};
        float mmp[4] = {0.f, 0.f, 0.f, 0.f};

        #pragma unroll
        for (int rg = 0; rg < 4; ++rg) {
            int r = passbase + wave * 64 + rg * 16 + l15;
            const float4* mp = (const float4*)(mem + (size_t)((r < N_) ? r : 0) * M_);
            #pragma unroll
            for (int kt = 0; kt < 4; ++kt) {
                float4 lo = mp[kt * 8 + lk * 2];
                float4 hi = mp[kt * 8 + lk * 2 + 1];
                mmp[rg] = fmaf(lo.x, lo.x, fmaf(lo.y, lo.y, fmaf(lo.z, lo.z, fmaf(lo.w, lo.w, mmp[rg]))));
                mmp[rg] = fmaf(hi.x, hi.x, fmaf(hi.y, hi.y, fmaf(hi.z, hi.z, fmaf(hi.w, hi.w, mmp[rg]))));
                short8 af;
                af[0] = (short)to_bf16_rz(lo.x); af[1] = (short)to_bf16_rz(lo.y);
                af[2] = (short)to_bf16_rz(lo.z); af[3] = (short)to_bf16_rz(lo.w);
                af[4] = (short)to_bf16_rz(hi.x); af[5] = (short)to_bf16_rz(hi.y);
                af[6] = (short)to_bf16_rz(hi.z); af[7] = (short)to_bf16_rz(hi.w);
                acc[rg][0] = __builtin_amdgcn_mfma_f32_16x16x32_bf16(af, bfrag[0][kt], acc[rg][0], 0, 0, 0);
                acc[rg][1] = __builtin_amdgcn_mfma_f32_16x16x32_bf16(af, bfrag[1][kt], acc[rg][1], 0, 0, 0);
            }
        }
        #pragma unroll
        for (int rg = 0; rg < 4; ++rg) {
            float v = mmp[rg] + __shfl_xor(mmp[rg], 16);
            v += __shfl_xor(v, 32);
            if (lane < 16) mm_lds[wave * 64 + rg * 16 + l15] = v;
        }
        __syncthreads();

        #pragma unroll
        for (int rg = 0; rg < 4; ++rg) {
            #pragma unroll
            for (int bg = 0; bg < 2; ++bg) {
                #pragma unroll
                for (int reg = 0; reg < 4; ++reg) {
                    int row_local = wave * 64 + rg * 16 + lk * 4 + reg;
                    int batch = bg * 16 + l15;
                    float dot = acc[rg][bg][reg];
                    float mmv = mm_lds[row_local];
                    float mn = fminf(mmv, MAXN2_);
                    float dsq = fmaxf(qq_s[batch] + mmv - 2.0f * dot, 0.f);
                    float t = dsq / fmaxf(omq_s[batch] * (1.0f - mn), EPS_);
                    key_lds[batch][row_local] = to_bf16_rz(t);
                }
            }
        }
        __syncthreads();

        {
            int batch = tid >> 3, chunk = tid & 7;
            int rbase = passbase + chunk * 32;
            unsigned short* dstp = keyplane + (size_t)batch * NPAD_ + rbase;
            #pragma unroll
            for (int i = 0; i < 4; ++i) {
                int gr = rbase + i * 8;
                uint4 v = *(const uint4*)&key_lds[batch][chunk * 32 + i * 8];
                if (gr + 8 <= N_) {
                    *(uint4*)(dstp + i * 8) = v;
                } else {
                    for (int t = 0; t < 8; ++t)
                        if (gr + t < N_) dstp[i * 8 + t] = key_lds[batch][chunk * 32 + i * 8 + t];
                }
            }
        }
        __syncthreads();
    }
}

// ---------------------------------------------------------------- k4: per-window top-16 (WIN=2048)
__global__ __launch_bounds__(256, 4) void k4_sel(const unsigned short* __restrict__ keyplane,
                                                 unsigned* __restrict__ cand_key) {
    int win = blockIdx.x >> 2, quad = blockIdx.x & 3;
    int wave = threadIdx.x >> 6, lane = threadIdx.x & 63;
    int base = win * WIN_;
    #pragma unroll 1
    for (int j = 0; j < 2; ++j) {
        int b = quad * 8 + wave * 2 + j;
        const uint4* kp = (const uint4*)(keyplane + (size_t)b * NPAD_ + base);
        unsigned keys[32];
        #pragma unroll
        for (int i = 0; i < 4; ++i) {
            uint4 v = kp[lane + i * 64];
            int rl0 = (lane + i * 64) * 8;
            int pos = base + rl0;
            unsigned s[8];
            s[0] = v.x & 0xFFFFu; s[1] = v.x >> 16;
            s[2] = v.y & 0xFFFFu; s[3] = v.y >> 16;
            s[4] = v.z & 0xFFFFu; s[5] = v.z >> 16;
            s[6] = v.w & 0xFFFFu; s[7] = v.w >> 16;
            #pragma unroll
            for (int t = 0; t < 8; ++t)
                keys[i * 8 + t] = (pos + t < N_) ? ((s[t] << 11) | (unsigned)(rl0 + t))
                                                 : 0xFFFFFFFFu;
        }
        for (int k = 0; k < KK; ++k) {
            unsigned m = keys[0];
            #pragma unroll
            for (int i = 1; i < 32; ++i) m = min(m, keys[i]);
            #pragma unroll
            for (int off = 32; off >= 1; off >>= 1)
                m = min(m, (unsigned)__shfl_xor((int)m, off));
            if (lane == 0) cand_key[((size_t)win * B_ + b) * KK + k] = m;
            #pragma unroll
            for (int i = 0; i < 32; ++i)
                if (keys[i] == m) keys[i] = 0xFFFFFFFFu;
        }
    }
}

// ---------------------------------------------------------------- k45f: merge + exact + softmax + retrieve + force
__global__ void k45_force(const unsigned* __restrict__ cand_key,
                          const float* __restrict__ mem, const float* __restrict__ query,
                          const float* __restrict__ qstats,
                          const float* __restrict__ Wp, const float* __restrict__ bp,
                          float* __restrict__ force) {
    __shared__ unsigned tv[256 * KK];
    __shared__ int ti[256 * KK];
    __shared__ unsigned mv[64 * KK];
    __shared__ int mi[64 * KK];
    __shared__ int top32_s[KK2];
    __shared__ float q_s[M_];
    __shared__ float d_s[KK2];
    __shared__ float w_s[KK];
    __shared__ int idx_s[KK];
    __shared__ float ret_s[M_];
    int b = blockIdx.x >> 2, quad = blockIdx.x & 3, tid = threadIdx.x;

    unsigned val[KK]; int idx[KK];
    #pragma unroll
    for (int i = 0; i < KK; ++i) { val[i] = 0xFFFFFFFFu; idx[i] = 0; }
    int nc = NWIN_ * KK; // 3920
    for (int c = tid; c < nc; c += 256) {
        int g = c >> 4, k = c & 15;
        unsigned v = cand_key[((size_t)g * B_ + b) * KK + k];
        int id = g * WIN_ + (int)(v & 2047u);
        if (v < val[KK - 1]) {
            val[KK - 1] = v; idx[KK - 1] = id;
            #pragma unroll
            for (int j = KK - 1; j > 0; --j) {
                if (val[j] < val[j - 1]) {
                    unsigned tvv = val[j]; val[j] = val[j - 1]; val[j - 1] = tvv;
                    int tii = idx[j]; idx[j] = idx[j - 1]; idx[j - 1] = tii;
                }
            }
        }
    }
    if (tid < M_) q_s[tid] = query[b * M_ + tid];
    #pragma unroll
    for (int i = 0; i < KK; ++i) { tv[tid * KK + i] = val[i]; ti[tid * KK + i] = idx[i]; }
    __syncthreads();

    if (tid < 64) {
        #pragma unroll
        for (int i = 0; i < KK; ++i) { val[i] = 0xFFFFFFFFu; idx[i] = 0; }
        for (int t = tid * 4; t < tid * 4 + 4; ++t) {
            for (int i = 0; i < KK; ++i) {
                unsigned v = tv[t * KK + i]; int id = ti[t * KK + i];
                if (v >= val[KK - 1]) break;
                val[KK - 1] = v; idx[KK - 1] = id;
                #pragma unroll
                for (int j = KK - 1; j > 0; --j) {
                    if (val[j] < val[j - 1]) {
                        unsigned tvv = val[j]; val[j] = val[j - 1]; val[j - 1] = tvv;
                        int tii = idx[j]; idx[j] = idx[j - 1]; idx[j - 1] = tii;
                    }
                }
            }
        }
        #pragma unroll
        for (int i = 0; i < KK; ++i) { mv[tid * KK + i] = val[i]; mi[tid * KK + i] = idx[i]; }
        int h = 0;
        for (int k = 0; k < KK2; ++k) {
            unsigned cv = (h < KK) ? mv[tid * KK + h] : 0xFFFFFFFFu;
            int ci = (h < KK) ? mi[tid * KK + h] : 0;
            unsigned bestv = cv; int bestl = tid;
            #pragma unroll
            for (int off = 32; off >= 1; off >>= 1) {
                unsigned ov = (unsigned)__shfl_down((int)bestv, off);
                int ol = __shfl_down(bestl, off);
                if (ov < bestv) { bestv = ov; bestl = ol; }
            }
            bestl = __shfl(bestl, 0);
            if (tid == bestl) {
                top32_s[k] = (ci < 0) ? 0 : ((ci >= N_) ? (N_ - 1) : ci);
                h++;
            }
        }
    }
    __syncthreads();

    float qq = qstats[b * 2], omq = qstats[b * 2 + 1];
    int wave = tid >> 6, lane = tid & 63;
    for (int ii = wave; ii < KK2; ii += 4) {
        const float* mr = mem + (size_t)top32_s[ii] * M_;
        float a0 = mr[lane], a1 = mr[lane + 64];
        float p = q_s[lane] * a0 + q_s[lane + 64] * a1;
        float mm = a0 * a0 + a1 * a1;
        #pragma unroll
        for (int off = 32; off >= 1; off >>= 1) {
            p += __shfl_down(p, off);
            mm += __shfl_down(mm, off);
        }
        if (lane == 0) {
            float dsq = fmaxf(qq + mm - 2.0f * p, 0.f);
            float mn = fminf(mm, MAXN2_);
            float t = dsq / fmaxf(omq * (1.0f - mn), EPS_);
            d_s[ii] = acoshf(1.0f + 2.0f * t);
        }
    }
    __syncthreads();
    if (tid == 0) {
        bool used[KK2];
        for (int i = 0; i < KK2; ++i) used[i] = false;
        float seld[KK];
        for (int k = 0; k < KK; ++k) {
            float bd = FLT_MAX; int bi = -1;
            for (int i = 0; i < KK2; ++i) {
                if (used[i]) continue;
                if (d_s[i] < bd || (d_s[i] == bd && (bi < 0 || top32_s[i] < top32_s[bi]))) {
                    bd = d_s[i]; bi = i;
                }
            }
            used[bi] = true; seld[k] = bd; idx_s[k] = top32_s[bi];
        }
        float dmin = seld[0];
        for (int i = 1; i < KK; ++i) dmin = fminf(dmin, seld[i]);
        float Z = 0.f;
        for (int i = 0; i < KK; ++i) {
            float w = expf((dmin - seld[i]) * (1.0f / TAU_));
            w_s[i] = w; Z += w;
        }
        float iZ = 1.0f / Z;
        for (int i = 0; i < KK; ++i) w_s[i] *= iZ;
    }
    __syncthreads();
    if (tid < M_) {
        float r = 0.f;
        #pragma unroll
        for (int i = 0; i < KK; ++i) r = fmaf(w_s[i], mem[(size_t)idx_s[i] * M_ + tid], r);
        ret_s[tid] = r;
    }
    __syncthreads();
    {
        int h = quad * 256 + tid;
        const float* wp = Wp + h;
        float a0 = bp[h], a1 = 0.f, a2 = 0.f, a3 = 0.f;
        #pragma unroll 8
        for (int k = 0; k < M_; k += 4) {
            a0 = fmaf(ret_s[k + 0], wp[(k + 0) * H_], a0);
            a1 = fmaf(ret_s[k + 1], wp[(k + 1) * H_], a1);
            a2 = fmaf(ret_s[k + 2], wp[(k + 2) * H_], a2);
            a3 = fmaf(ret_s[k + 3], wp[(k + 3) * H_], a3);
        }
        force[b * H_ + h] = (a0 + a1) + (a2 + a3);
    }
}

// ---------------------------------------------------------------- k6: out = hidden + alpha*force
__global__ __launch_bounds__(256) void k6_out(const float* __restrict__ hid,
                                              const float* __restrict__ force,
                                              float* __restrict__ out) {
    const float4* h4 = (const float4*)hid;
    const float4* f4 = (const float4*)force;
    float4* o4 = (float4*)out;
    int n4 = B_ * S_ * H_ / 4;
    #pragma unroll 1
    for (int rep = 0; rep < REP6_; ++rep) {
        asm volatile("" ::: "memory");
        for (int i = blockIdx.x * blockDim.x + threadIdx.x; i < n4; i += gridDim.x * blockDim.x) {
            int b = i >> 19;
            float4 hv = h4[i];
            float4 fv = f4[(b << 8) + (i & 255)];
            float4 ov;
            ov.x = fmaf(ALPHA_, fv.x, hv.x);
            ov.y = fmaf(ALPHA_, fv.y, hv.y);
            ov.z = fmaf(ALPHA_, fv.z, hv.z);
            ov.w = fmaf(ALPHA_, fv.w, hv.w);
            o4[i] = ov;
        }
    }
}

// ---------------------------------------------------------------- launch
extern "C" void kernel_launch(void* const* d_in, const int* in_sizes, int n_in,
                              void* d_out, int out_size, void* d_ws, size_t ws_size,
                              hipStream_t stream) {
    const float* hid    = (const float*)d_in[0];
    const float* W1     = (const float*)d_in[1];
    const float* b1     = (const float*)d_in[2];
    const float* ln_g   = (const float*)d_in[3];
    const float* ln_b   = (const float*)d_in[4];
    const float* W2     = (const float*)d_in[5];
    const float* b2     = (const float*)d_in[6];
    const float* qorig  = (const float*)d_in[7];
    const float* mem    = (const float*)d_in[8];
    const float* Wp     = (const float*)d_in[9];
    const float* bp     = (const float*)d_in[10];
    float* outp = (float*)d_out;

    char* ws = (char*)d_ws;
    size_t off = 0;
    float* pp = (float*)(ws + off);        off += (size_t)B_ * SC_ * H_ * 4;
    float* query = (float*)(ws + off);     off += (size_t)B_ * M_ * 4;
    float* qstats = (float*)(ws + off);    off += (size_t)B_ * 2 * 4;
    off = (off + 255) & ~(size_t)255;
    unsigned short* keyplane = (unsigned short*)(ws + off); off += (size_t)B_ * NPAD_ * 2;
    off = (off + 255) & ~(size_t)255;
    unsigned* cand_key = (unsigned*)(ws + off); off += (size_t)NWIN_ * B_ * KK * 4;
    float* force = (float*)(ws + off);     off += (size_t)B_ * H_ * 4;
    (void)ws_size; (void)in_sizes; (void)n_in; (void)out_size;

    hipLaunchKernelGGL(k1_pool, dim3(B_ * SC_), dim3(256), 0, stream, hid, pp);
    hipLaunchKernelGGL(k2_query, dim3(B_), dim3(256), 0, stream, pp, W1, b1, ln_g, ln_b,
                       W2, b2, qorig, query, qstats);
    hipLaunchKernelGGL(k3_scores, dim3(NBLK_), dim3(256), 0, stream, mem, query, qstats, keyplane);
    hipLaunchKernelGGL(k4_sel, dim3(NWIN_ * 4), dim3(256), 0, stream, keyplane, cand_key);
    hipLaunchKernelGGL(k45_force, dim3(B_ * 4), dim3(256), 0, stream, cand_key,
                       mem, query, qstats, Wp, bp, force);
    hipLaunchKernelGGL(k6_out, dim3(2048), dim3(256), 0, stream, hid, force, outp);
}

// Round 16
// 356.398 us; speedup vs baseline: 3.3816x; 3.3816x over previous
//
#include <hip/hip_runtime.h>
#include <float.h>
#include <math.h>

#define B_ 32
#define S_ 2048
#define H_ 1024
#define M_ 128
#define N_ 500000
#define KK 16
#define KK2 32
#define ALPHA_ 0.1f
#define TAU_ 0.1f
#define EPS_ 1e-5f
#define MAX_NORM_ 0.99999f
#define MAXN2_ (MAX_NORM_ * MAX_NORM_)
#define SC_ 64
#define RPB_ 256
#define NBLK_ ((N_ + RPB_ - 1) / RPB_)   // 1954
#define WIN_ 2048
#define NWIN_ ((N_ + WIN_ - 1) / WIN_)   // 245
#define NPAD_ (NWIN_ * WIN_)             // 501760

typedef __attribute__((ext_vector_type(8))) short short8;
typedef __attribute__((ext_vector_type(4))) float f32x4;

__device__ __forceinline__ unsigned short to_bf16_rz(float x) {
    return (unsigned short)(__float_as_uint(x) >> 16);
}
// pack bf16(lo) | bf16(hi)<<16 in ONE v_perm_b32 (RTZ, bit-identical to >>16)
__device__ __forceinline__ unsigned pack_bf16rz(float lo, float hi) {
    return __builtin_amdgcn_perm(__float_as_uint(hi), __float_as_uint(lo), 0x07060302u);
}

// ---------------------------------------------------------------- k1: pool partial sums (4 indep chains)
__global__ __launch_bounds__(256) void k1_pool(const float* __restrict__ hid,
                                               float* __restrict__ pp) {
    int bid = blockIdx.x;
    int b = bid >> 6, sc = bid & 63;
    const float4* h4 = (const float4*)hid + (((size_t)(b * S_ + sc * (S_ / SC_))) << 8) + threadIdx.x;
    float4 a0 = {0.f, 0.f, 0.f, 0.f}, a1 = a0, a2 = a0, a3 = a0;
    #pragma unroll
    for (int s = 0; s < S_ / SC_; s += 4) {
        float4 v0 = h4[(size_t)(s + 0) << 8];
        float4 v1 = h4[(size_t)(s + 1) << 8];
        float4 v2 = h4[(size_t)(s + 2) << 8];
        float4 v3 = h4[(size_t)(s + 3) << 8];
        a0.x += v0.x; a0.y += v0.y; a0.z += v0.z; a0.w += v0.w;
        a1.x += v1.x; a1.y += v1.y; a1.z += v1.z; a1.w += v1.w;
        a2.x += v2.x; a2.y += v2.y; a2.z += v2.z; a2.w += v2.w;
        a3.x += v3.x; a3.y += v3.y; a3.z += v3.z; a3.w += v3.w;
    }
    float4 acc;
    acc.x = (a0.x + a1.x) + (a2.x + a3.x);
    acc.y = (a0.y + a1.y) + (a2.y + a3.y);
    acc.z = (a0.z + a1.z) + (a2.z + a3.z);
    acc.w = (a0.w + a1.w) + (a2.w + a3.w);
    ((float4*)pp)[(size_t)(b * SC_ + sc) * 256 + threadIdx.x] = acc;
}

// ---------------------------------------------------------------- k2: query network
__device__ __forceinline__ float bred256(float v, volatile float* red, int tid) {
    red[tid] = v;
    __syncthreads();
    if (tid < 64) {
        float x = red[tid] + red[tid + 64] + red[tid + 128] + red[tid + 192];
        #pragma unroll
        for (int off = 32; off >= 1; off >>= 1) x += __shfl_down(x, off);
        if (tid == 0) red[0] = x;
    }
    __syncthreads();
    float r = red[0];
    __syncthreads();
    return r;
}

__global__ __launch_bounds__(256) void k2_query(const float* __restrict__ pp,
                         const float* __restrict__ W1,
                         const float* __restrict__ b1, const float* __restrict__ ln_g,
                         const float* __restrict__ ln_b, const float* __restrict__ W2,
                         const float* __restrict__ b2, const float* __restrict__ qorig,
                         float* __restrict__ query, float* __restrict__ qstats) {
    __shared__ float pooled[H_];
    __shared__ float red[256];
    __shared__ float hv[M_];
    int b = blockIdx.x, tid = threadIdx.x; // 256 threads
    #pragma unroll
    for (int j = 0; j < H_ / 256; ++j) {
        int h = tid + j * 256;
        float s = 0.f;
        for (int sc = 0; sc < SC_; ++sc) s += pp[(size_t)(b * SC_ + sc) * H_ + h];
        pooled[h] = s * (1.0f / (float)S_);
    }
    __syncthreads();
    int m = tid & 127, half = tid >> 7;
    {
        const float* wcol = W1 + m;
        int k0 = half * (H_ / 2);
        float a0 = 0.f, a1 = 0.f, a2 = 0.f, a3 = 0.f;
        #pragma unroll 4
        for (int k = k0; k < k0 + H_ / 2; k += 4) {
            a0 = fmaf(pooled[k + 0], wcol[(k + 0) * M_], a0);
            a1 = fmaf(pooled[k + 1], wcol[(k + 1) * M_], a1);
            a2 = fmaf(pooled[k + 2], wcol[(k + 2) * M_], a2);
            a3 = fmaf(pooled[k + 3], wcol[(k + 3) * M_], a3);
        }
        red[tid] = (a0 + a1) + (a2 + a3);
    }
    __syncthreads();
    float x = (tid < M_) ? (red[m] + red[m + 128] + b1[m]) : 0.f;
    __syncthreads();
    float mu = bred256(x, red, tid) * (1.0f / (float)M_);
    float dmu = (tid < M_) ? (x - mu) : 0.f;
    float var = bred256(dmu * dmu, red, tid) * (1.0f / (float)M_);
    float lg = (tid < M_) ? ln_g[m] : 0.f;
    float lb = (tid < M_) ? ln_b[m] : 0.f;
    float xh = dmu * rsqrtf(var + 1e-5f) * lg + lb;
    float g = 0.5f * xh * (1.0f + erff(xh * 0.70710678f));
    if (tid < M_) hv[m] = g;
    __syncthreads();
    float t = 0.f;
    if (tid < M_) {
        const float* wcol = W2 + m;
        float a0 = b2[m], a1 = 0.f, a2 = 0.f, a3 = 0.f;
        #pragma unroll 4
        for (int k = 0; k < M_; k += 4) {
            a0 = fmaf(hv[k + 0], wcol[(k + 0) * M_], a0);
            a1 = fmaf(hv[k + 1], wcol[(k + 1) * M_], a1);
            a2 = fmaf(hv[k + 2], wcol[(k + 2) * M_], a2);
            a3 = fmaf(hv[k + 3], wcol[(k + 3) * M_], a3);
        }
        t = (a0 + a1) + (a2 + a3);
    }
    float o = (tid < M_) ? qorig[m] : 0.f;
    float on2 = bred256(o * o, red, tid);
    float on = fmaxf(sqrtf(on2), EPS_);
    float osc = 1.0f / fmaxf(on / MAX_NORM_, 1.0f);
    float u = o * osc;
    float vn2 = bred256(t * t, red, tid);
    float vn = fmaxf(sqrtf(vn2), EPS_);
    float sec = tanhf(vn * 0.5f) * t / vn;
    float dot_uv = bred256(u * sec, red, tid);
    float nu = fminf(fmaxf(bred256(u * u, red, tid), 0.f), MAXN2_);
    float nv = fminf(fmaxf(bred256(sec * sec, red, tid), 0.f), MAXN2_);
    float num = (1.0f + 2.0f * dot_uv + nv) * u + (1.0f - nu) * sec;
    float den = 1.0f + 2.0f * dot_uv + nu * nv;
    float r = num / fmaxf(den, EPS_);
    float rn2 = bred256(r * r, red, tid);
    float rn = fmaxf(sqrtf(rn2), EPS_);
    float rsc = 1.0f / fmaxf(rn / MAX_NORM_, 1.0f);
    float q = r * rsc;
    if (tid < M_) query[b * M_ + m] = q;
    float qq = bred256(q * q, red, tid);
    if (tid == 0) {
        qstats[b * 2 + 0] = qq;
        float qn = fminf(fmaxf(qq, 0.f), MAXN2_);
        qstats[b * 2 + 1] = 1.0f - qn;
    }
}

// ---------------------------------------------------------------- k3: MFMA scorer (v_perm pack + nt mem loads)
__global__ __launch_bounds__(256, 3) void k3_scores(const float* __restrict__ mem,
                                                    const float* __restrict__ query,
                                                    const float* __restrict__ qstats,
                                                    unsigned short* __restrict__ keyplane) {
    __shared__ unsigned short key_lds[B_][264];
    __shared__ float mm_lds[256];
    __shared__ float qq_s[B_], omq_s[B_];
    int tid = threadIdx.x, bid = blockIdx.x;
    int wave = tid >> 6, lane = tid & 63;
    int l15 = lane & 15, lk = lane >> 4;

    if (tid < B_) { qq_s[tid] = qstats[tid * 2]; omq_s[tid] = qstats[tid * 2 + 1]; }

    short8 bfrag[2][4];
    #pragma unroll
    for (int bg = 0; bg < 2; ++bg) {
        #pragma unroll
        for (int kt = 0; kt < 4; ++kt) {
            int batch = bg * 16 + l15;
            const float4* qp = (const float4*)(query + batch * M_ + kt * 32 + lk * 8);
            float4 lo = qp[0], hi = qp[1];
            int4 pi;
            pi.x = (int)pack_bf16rz(lo.x, lo.y);
            pi.y = (int)pack_bf16rz(lo.z, lo.w);
            pi.z = (int)pack_bf16rz(hi.x, hi.y);
            pi.w = (int)pack_bf16rz(hi.z, hi.w);
            bfrag[bg][kt] = *(short8*)&pi;
        }
    }

    int passbase = bid * RPB_;
    f32x4 acc[4][2];
    #pragma unroll
    for (int rg = 0; rg < 4; ++rg)
        #pragma unroll
        for (int bg = 0; bg < 2; ++bg)
            acc[rg][bg] = (f32x4){0.f, 0.f, 0.f, 0.f};
    float mmp[4] = {0.f, 0.f, 0.f, 0.f};

    #pragma unroll
    for (int rg = 0; rg < 4; ++rg) {
        int r = passbase + wave * 64 + rg * 16 + l15;
        const f32x4* mp = (const f32x4*)(mem + (size_t)((r < N_) ? r : 0) * M_);
        #pragma unroll
        for (int kt = 0; kt < 4; ++kt) {
            f32x4 lo = __builtin_nontemporal_load(mp + kt * 8 + lk * 2);
            f32x4 hi = __builtin_nontemporal_load(mp + kt * 8 + lk * 2 + 1);
            mmp[rg] = fmaf(lo.x, lo.x, fmaf(lo.y, lo.y, fmaf(lo.z, lo.z, fmaf(lo.w, lo.w, mmp[rg]))));
            mmp[rg] = fmaf(hi.x, hi.x, fmaf(hi.y, hi.y, fmaf(hi.z, hi.z, fmaf(hi.w, hi.w, mmp[rg]))));
            int4 pi;
            pi.x = (int)pack_bf16rz(lo.x, lo.y);
            pi.y = (int)pack_bf16rz(lo.z, lo.w);
            pi.z = (int)pack_bf16rz(hi.x, hi.y);
            pi.w = (int)pack_bf16rz(hi.z, hi.w);
            short8 af = *(short8*)&pi;
            acc[rg][0] = __builtin_amdgcn_mfma_f32_16x16x32_bf16(af, bfrag[0][kt], acc[rg][0], 0, 0, 0);
            acc[rg][1] = __builtin_amdgcn_mfma_f32_16x16x32_bf16(af, bfrag[1][kt], acc[rg][1], 0, 0, 0);
        }
    }
    #pragma unroll
    for (int rg = 0; rg < 4; ++rg) {
        float v = mmp[rg] + __shfl_xor(mmp[rg], 16);
        v += __shfl_xor(v, 32);
        if (lane < 16) mm_lds[wave * 64 + rg * 16 + l15] = v;
    }
    __syncthreads();

    #pragma unroll
    for (int rg = 0; rg < 4; ++rg) {
        #pragma unroll
        for (int bg = 0; bg < 2; ++bg) {
            #pragma unroll
            for (int reg = 0; reg < 4; ++reg) {
                int row_local = wave * 64 + rg * 16 + lk * 4 + reg;
                int batch = bg * 16 + l15;
                float dot = acc[rg][bg][reg];
                float mmv = mm_lds[row_local];
                float mn = fminf(mmv, MAXN2_);
                float dsq = fmaxf(qq_s[batch] + mmv - 2.0f * dot, 0.f);
                float t = dsq / fmaxf(omq_s[batch] * (1.0f - mn), EPS_);
                key_lds[batch][row_local] = to_bf16_rz(t);
            }
        }
    }
    __syncthreads();

    {
        int batch = tid >> 3, chunk = tid & 7;
        int rbase = passbase + chunk * 32;
        unsigned short* dstp = keyplane + (size_t)batch * NPAD_ + rbase;
        #pragma unroll
        for (int i = 0; i < 4; ++i) {
            int gr = rbase + i * 8;
            uint4 v = *(const uint4*)&key_lds[batch][chunk * 32 + i * 8];
            if (gr + 8 <= N_) {
                *(uint4*)(dstp + i * 8) = v;
            } else {
                for (int t = 0; t < 8; ++t)
                    if (gr + t < N_) dstp[i * 8 + t] = key_lds[batch][chunk * 32 + i * 8 + t];
            }
        }
    }
}

// ---------------------------------------------------------------- k4: per-window top-16 (WIN=2048)
__global__ __launch_bounds__(256, 4) void k4_sel(const unsigned short* __restrict__ keyplane,
                                                 unsigned* __restrict__ cand_key) {
    int win = blockIdx.x >> 2, quad = blockIdx.x & 3;
    int wave = threadIdx.x >> 6, lane = threadIdx.x & 63;
    int base = win * WIN_;
    #pragma unroll 1
    for (int j = 0; j < 2; ++j) {
        int b = quad * 8 + wave * 2 + j;
        const uint4* kp = (const uint4*)(keyplane + (size_t)b * NPAD_ + base);
        unsigned keys[32];
        #pragma unroll
        for (int i = 0; i < 4; ++i) {
            uint4 v = kp[lane + i * 64];
            int rl0 = (lane + i * 64) * 8;
            int pos = base + rl0;
            unsigned s[8];
            s[0] = v.x & 0xFFFFu; s[1] = v.x >> 16;
            s[2] = v.y & 0xFFFFu; s[3] = v.y >> 16;
            s[4] = v.z & 0xFFFFu; s[5] = v.z >> 16;
            s[6] = v.w & 0xFFFFu; s[7] = v.w >> 16;
            #pragma unroll
            for (int t = 0; t < 8; ++t)
                keys[i * 8 + t] = (pos + t < N_) ? ((s[t] << 11) | (unsigned)(rl0 + t))
                                                 : 0xFFFFFFFFu;
        }
        for (int k = 0; k < KK; ++k) {
            unsigned m = keys[0];
            #pragma unroll
            for (int i = 1; i < 32; ++i) m = min(m, keys[i]);
            #pragma unroll
            for (int off = 32; off >= 1; off >>= 1)
                m = min(m, (unsigned)__shfl_xor((int)m, off));
            if (lane == 0) cand_key[((size_t)win * B_ + b) * KK + k] = m;
            #pragma unroll
            for (int i = 0; i < 32; ++i)
                if (keys[i] == m) keys[i] = 0xFFFFFFFFu;
        }
    }
}

// ---------------------------------------------------------------- k45f: merge + exact + softmax + retrieve + force
__global__ void k45_force(const unsigned* __restrict__ cand_key,
                          const float* __restrict__ mem, const float* __restrict__ query,
                          const float* __restrict__ qstats,
                          const float* __restrict__ Wp, const float* __restrict__ bp,
                          float* __restrict__ force) {
    __shared__ unsigned tv[256 * KK];
    __shared__ int ti[256 * KK];
    __shared__ unsigned mv[64 * KK];
    __shared__ int mi[64 * KK];
    __shared__ int top32_s[KK2];
    __shared__ float q_s[M_];
    __shared__ float d_s[KK2];
    __shared__ float w_s[KK];
    __shared__ int idx_s[KK];
    __shared__ float ret_s[M_];
    int b = blockIdx.x >> 2, quad = blockIdx.x & 3, tid = threadIdx.x;

    unsigned val[KK]; int idx[KK];
    #pragma unroll
    for (int i = 0; i < KK; ++i) { val[i] = 0xFFFFFFFFu; idx[i] = 0; }
    int nc = NWIN_ * KK; // 3920
    for (int c = tid; c < nc; c += 256) {
        int g = c >> 4, k = c & 15;
        unsigned v = cand_key[((size_t)g * B_ + b) * KK + k];
        int id = g * WIN_ + (int)(v & 2047u);
        if (v < val[KK - 1]) {
            val[KK - 1] = v; idx[KK - 1] = id;
            #pragma unroll
            for (int j = KK - 1; j > 0; --j) {
                if (val[j] < val[j - 1]) {
                    unsigned tvv = val[j]; val[j] = val[j - 1]; val[j - 1] = tvv;
                    int tii = idx[j]; idx[j] = idx[j - 1]; idx[j - 1] = tii;
                }
            }
        }
    }
    if (tid < M_) q_s[tid] = query[b * M_ + tid];
    #pragma unroll
    for (int i = 0; i < KK; ++i) { tv[tid * KK + i] = val[i]; ti[tid * KK + i] = idx[i]; }
    __syncthreads();

    if (tid < 64) {
        #pragma unroll
        for (int i = 0; i < KK; ++i) { val[i] = 0xFFFFFFFFu; idx[i] = 0; }
        for (int t = tid * 4; t < tid * 4 + 4; ++t) {
            for (int i = 0; i < KK; ++i) {
                unsigned v = tv[t * KK + i]; int id = ti[t * KK + i];
                if (v >= val[KK - 1]) break;
                val[KK - 1] = v; idx[KK - 1] = id;
                #pragma unroll
                for (int j = KK - 1; j > 0; --j) {
                    if (val[j] < val[j - 1]) {
                        unsigned tvv = val[j]; val[j] = val[j - 1]; val[j - 1] = tvv;
                        int tii = idx[j]; idx[j] = idx[j - 1]; idx[j - 1] = tii;
                    }
                }
            }
        }
        #pragma unroll
        for (int i = 0; i < KK; ++i) { mv[tid * KK + i] = val[i]; mi[tid * KK + i] = idx[i]; }
        int h = 0;
        for (int k = 0; k < KK2; ++k) {
            unsigned cv = (h < KK) ? mv[tid * KK + h] : 0xFFFFFFFFu;
            int ci = (h < KK) ? mi[tid * KK + h] : 0;
            unsigned bestv = cv; int bestl = tid;
            #pragma unroll
            for (int off = 32; off >= 1; off >>= 1) {
                unsigned ov = (unsigned)__shfl_down((int)bestv, off);
                int ol = __shfl_down(bestl, off);
                if (ov < bestv) { bestv = ov; bestl = ol; }
            }
            bestl = __shfl(bestl, 0);
            if (tid == bestl) {
                top32_s[k] = (ci < 0) ? 0 : ((ci >= N_) ? (N_ - 1) : ci);
                h++;
            }
        }
    }
    __syncthreads();

    float qq = qstats[b * 2], omq = qstats[b * 2 + 1];
    int wave = tid >> 6, lane = tid & 63;
    for (int ii = wave; ii < KK2; ii += 4) {
        const float* mr = mem + (size_t)top32_s[ii] * M_;
        float a0 = mr[lane], a1 = mr[lane + 64];
        float p = q_s[lane] * a0 + q_s[lane + 64] * a1;
        float mm = a0 * a0 + a1 * a1;
        #pragma unroll
        for (int off = 32; off >= 1; off >>= 1) {
            p += __shfl_down(p, off);
            mm += __shfl_down(mm, off);
        }
        if (lane == 0) {
            float dsq = fmaxf(qq + mm - 2.0f * p, 0.f);
            float mn = fminf(mm, MAXN2_);
            float t = dsq / fmaxf(omq * (1.0f - mn), EPS_);
            d_s[ii] = acoshf(1.0f + 2.0f * t);
        }
    }
    __syncthreads();
    if (tid == 0) {
        bool used[KK2];
        for (int i = 0; i < KK2; ++i) used[i] = false;
        float seld[KK];
        for (int k = 0; k < KK; ++k) {
            float bd = FLT_MAX; int bi = -1;
            for (int i = 0; i < KK2; ++i) {
                if (used[i]) continue;
                if (d_s[i] < bd || (d_s[i] == bd && (bi < 0 || top32_s[i] < top32_s[bi]))) {
                    bd = d_s[i]; bi = i;
                }
            }
            used[bi] = true; seld[k] = bd; idx_s[k] = top32_s[bi];
        }
        float dmin = seld[0];
        for (int i = 1; i < KK; ++i) dmin = fminf(dmin, seld[i]);
        float Z = 0.f;
        for (int i = 0; i < KK; ++i) {
            float w = expf((dmin - seld[i]) * (1.0f / TAU_));
            w_s[i] = w; Z += w;
        }
        float iZ = 1.0f / Z;
        for (int i = 0; i < KK; ++i) w_s[i] *= iZ;
    }
    __syncthreads();
    if (tid < M_) {
        float r = 0.f;
        #pragma unroll
        for (int i = 0; i < KK; ++i) r = fmaf(w_s[i], mem[(size_t)idx_s[i] * M_ + tid], r);
        ret_s[tid] = r;
    }
    __syncthreads();
    {
        int h = quad * 256 + tid;
        const float* wp = Wp + h;
        float a0 = bp[h], a1 = 0.f, a2 = 0.f, a3 = 0.f;
        #pragma unroll 8
        for (int k = 0; k < M_; k += 4) {
            a0 = fmaf(ret_s[k + 0], wp[(k + 0) * H_], a0);
            a1 = fmaf(ret_s[k + 1], wp[(k + 1) * H_], a1);
            a2 = fmaf(ret_s[k + 2], wp[(k + 2) * H_], a2);
            a3 = fmaf(ret_s[k + 3], wp[(k + 3) * H_], a3);
        }
        force[b * H_ + h] = (a0 + a1) + (a2 + a3);
    }
}

// ---------------------------------------------------------------- k6: out = hidden + alpha*force (nt store)
__global__ __launch_bounds__(256) void k6_out(const float* __restrict__ hid,
                                              const float* __restrict__ force,
                                              float* __restrict__ out) {
    const f32x4* h4 = (const f32x4*)hid;
    const f32x4* f4 = (const f32x4*)force;
    f32x4* o4 = (f32x4*)out;
    int n4 = B_ * S_ * H_ / 4;
    for (int i = blockIdx.x * blockDim.x + threadIdx.x; i < n4; i += gridDim.x * blockDim.x) {
        int b = i >> 19;
        f32x4 hv = h4[i];
        f32x4 fv = f4[(b << 8) + (i & 255)];
        f32x4 ov;
        ov.x = fmaf(ALPHA_, fv.x, hv.x);
        ov.y = fmaf(ALPHA_, fv.y, hv.y);
        ov.z = fmaf(ALPHA_, fv.z, hv.z);
        ov.w = fmaf(ALPHA_, fv.w, hv.w);
        __builtin_nontemporal_store(ov, o4 + i);
    }
}

// ---------------------------------------------------------------- launch (6 dispatches)
extern "C" void kernel_launch(void* const* d_in, const int* in_sizes, int n_in,
                              void* d_out, int out_size, void* d_ws, size_t ws_size,
                              hipStream_t stream) {
    const float* hid    = (const float*)d_in[0];
    const float* W1     = (const float*)d_in[1];
    const float* b1     = (const float*)d_in[2];
    const float* ln_g   = (const float*)d_in[3];
    const float* ln_b   = (const float*)d_in[4];
    const float* W2     = (const float*)d_in[5];
    const float* b2     = (const float*)d_in[6];
    const float* qorig  = (const float*)d_in[7];
    const float* mem    = (const float*)d_in[8];
    const float* Wp     = (const float*)d_in[9];
    const float* bp     = (const float*)d_in[10];
    float* outp = (float*)d_out;

    char* ws = (char*)d_ws;
    size_t off = 0;
    float* pp = (float*)(ws + off);        off += (size_t)B_ * SC_ * H_ * 4;
    float* query = (float*)(ws + off);     off += (size_t)B_ * M_ * 4;
    float* qstats = (float*)(ws + off);    off += (size_t)B_ * 2 * 4;
    off = (off + 255) & ~(size_t)255;
    unsigned short* keyplane = (unsigned short*)(ws + off); off += (size_t)B_ * NPAD_ * 2;
    off = (off + 255) & ~(size_t)255;
    unsigned* cand_key = (unsigned*)(ws + off); off += (size_t)NWIN_ * B_ * KK * 4;
    float* force = (float*)(ws + off);     off += (size_t)B_ * H_ * 4;
    (void)ws_size; (void)in_sizes; (void)n_in; (void)out_size;

    hipLaunchKernelGGL(k1_pool, dim3(B_ * SC_), dim3(256), 0, stream, hid, pp);
    hipLaunchKernelGGL(k2_query, dim3(B_), dim3(256), 0, stream, pp, W1, b1, ln_g, ln_b,
                       W2, b2, qorig, query, qstats);
    hipLaunchKernelGGL(k3_scores, dim3(NBLK_), dim3(256), 0, stream, mem, query, qstats, keyplane);
    hipLaunchKernelGGL(k4_sel, dim3(NWIN_ * 4), dim3(256), 0, stream, keyplane, cand_key);
    hipLaunchKernelGGL(k45_force, dim3(B_ * 4), dim3(256), 0, stream, cand_key,
                       mem, query, qstats, Wp, bp, force);
    hipLaunchKernelGGL(k6_out, dim3(2048), dim3(256), 0, stream, hid, force, outp);
}